// Round 1
// baseline (534.478 us; speedup 1.0000x reference)
//
#include <hip/hip_runtime.h>
#include <hip/hip_bf16.h>

typedef __bf16 bf16;
typedef __attribute__((ext_vector_type(8))) __bf16 bf16x8;
typedef __attribute__((ext_vector_type(4))) float f32x4;

#define MFMA16x16x32 __builtin_amdgcn_mfma_f32_16x16x32_bf16

// Problem constants
#define NB 8
#define NC 512
#define NN 4096     // H*W
#define CFG 64

// -------------------- kernel 0: weight prep (fp32 -> bf16, concat) ----------
__global__ __launch_bounds__(256) void k_wprep(
    const float* __restrict__ Wf, const float* __restrict__ bfv,
    const float* __restrict__ Wg, const float* __restrict__ bgv,
    const float* __restrict__ Wh,
    bf16* __restrict__ Wfg, bf16* __restrict__ Whb, float* __restrict__ bfg)
{
    int idx = blockIdx.x * 256 + threadIdx.x;
    if (idx < 32768)       Wfg[idx] = (bf16)Wf[idx];
    else if (idx < 65536)  Wfg[idx] = (bf16)Wg[idx - 32768];
    if (idx < 262144)      Whb[idx] = (bf16)Wh[idx];
    if (idx < 64)          bfg[idx] = bfv[idx];
    else if (idx < 128)    bfg[idx] = bgv[idx - 64];
}

// -------------------- kernel 1: x [B][C][N] fp32 -> xT [B][N][C] bf16 -------
__global__ __launch_bounds__(256) void k_transpose(
    const float* __restrict__ x, bf16* __restrict__ xT)
{
    __shared__ bf16 tile[64][72];
    int b = blockIdx.z, c0 = blockIdx.y * 64, n0 = blockIdx.x * 64;
    int t = threadIdx.x;
    int cl  = t >> 2;
    int seg = (t & 3) * 16;
    const float* src = x + ((size_t)(b * NC + c0 + cl)) * NN + n0 + seg;
#pragma unroll
    for (int u = 0; u < 4; u++) {
        float4 v = ((const float4*)src)[u];
        tile[cl][seg + u*4 + 0] = (bf16)v.x;
        tile[cl][seg + u*4 + 1] = (bf16)v.y;
        tile[cl][seg + u*4 + 2] = (bf16)v.z;
        tile[cl][seg + u*4 + 3] = (bf16)v.w;
    }
    __syncthreads();
    int nl = t >> 2;
    int cs = (t & 3) * 16;
    bf16 buf[16];
#pragma unroll
    for (int u = 0; u < 16; u++) buf[u] = tile[cs + u][nl];
    bf16* dst = xT + ((size_t)(b * NN + n0 + nl)) * NC + c0 + cs;
    ((bf16x8*)dst)[0] = *(bf16x8*)&buf[0];
    ((bf16x8*)dst)[1] = *(bf16x8*)&buf[8];
}

// -------------------- kernel 2: generic bf16 NT-GEMM -----------------------
// D[i][j] = sum_k A[i][k] * B[j][k]  (+ bias[j] or bias[i]), D stored bf16.
// Each wave computes a 64x64 tile; 4 waves/block.
__global__ __launch_bounds__(256) void k_gemm_nt(
    const bf16* __restrict__ A, long long sAb, int lda,
    const bf16* __restrict__ Bm, long long sBb, int ldb,
    bf16* __restrict__ D, long long sDb, int ldd,
    const float* __restrict__ bias, int bias_row, int Nt, int K)
{
    int b = blockIdx.y;
    int w = threadIdx.x >> 6, l = threadIdx.x & 63;
    int tile = blockIdx.x * 4 + w;
    int ti = tile / Nt, tj = tile % Nt;
    int lr = l & 15, lq = l >> 4;

    const bf16* Ab = A + sAb * b + (size_t)(ti * 64) * lda;
    const bf16* Bb = Bm + sBb * b + (size_t)(tj * 64) * ldb;

    f32x4 acc[4][4] = {};
    for (int k0 = 0; k0 < K; k0 += 32) {
        bf16x8 a[4], bb[4];
#pragma unroll
        for (int fi = 0; fi < 4; fi++)
            a[fi] = *(const bf16x8*)(Ab + (size_t)(fi*16 + lr) * lda + k0 + lq*8);
#pragma unroll
        for (int fj = 0; fj < 4; fj++)
            bb[fj] = *(const bf16x8*)(Bb + (size_t)(fj*16 + lr) * ldb + k0 + lq*8);
#pragma unroll
        for (int fi = 0; fi < 4; fi++)
#pragma unroll
            for (int fj = 0; fj < 4; fj++)
                acc[fi][fj] = MFMA16x16x32(a[fi], bb[fj], acc[fi][fj], 0, 0, 0);
    }
#pragma unroll
    for (int fi = 0; fi < 4; fi++)
#pragma unroll
        for (int fj = 0; fj < 4; fj++)
#pragma unroll
            for (int t = 0; t < 4; t++) {
                int row = ti*64 + fi*16 + lq*4 + t;
                int col = tj*64 + fj*16 + lr;
                float v = acc[fi][fj][t] + (bias_row ? bias[row] : bias[col]);
                D[sDb * b + (size_t)row * ldd + col] = (bf16)v;
            }
}

// -------------------- kernel 3: fused attention -----------------------------
// fgT: [B][N][128] bf16 (cols 0-63 = f^T, 64-127 = g^T); h: [B][C][N] bf16.
// Block: 512 threads (8 waves), one 64-query tile. Unnormalized softmax:
// O = sum_j exp(s_ij) h[:,j]; l_i = sum_j exp(s_ij); out = gamma*O/l + x.
__global__ __launch_bounds__(512) void k_attn(
    const bf16* __restrict__ fgT, const bf16* __restrict__ h,
    const float* __restrict__ x, const float* __restrict__ gammap,
    float* __restrict__ out)
{
    __shared__ alignas(16) bf16 P[64][72];
    __shared__ alignas(16) float linv[64];

    int b = blockIdx.y;
    int i0 = blockIdx.x * 64;
    int w = threadIdx.x >> 6, l = threadIdx.x & 63;
    int lr = l & 15, lq = l >> 4;

    const bf16* fg = fgT + (size_t)b * NN * 128;
    const bf16* hb = h + (size_t)b * NC * NN;
    float gamma = *gammap;

    // S-tile assignment: wave w computes fragments (fi_s, fjb) and (fi_s, fjb+1)
    int fi_s = w >> 1;
    int fjb  = (w & 1) * 2;

    bf16x8 a_s[2];
#pragma unroll
    for (int ks = 0; ks < 2; ks++)
        a_s[ks] = *(const bf16x8*)(fg + (size_t)(i0 + fi_s*16 + lr) * 128 + 64 + ks*32 + lq*8);

    f32x4 oacc[4][4] = {};
    float lacc[4] = {0.f, 0.f, 0.f, 0.f};
    int cw = w * 64;

    for (int j0 = 0; j0 < NN; j0 += 64) {
        // ---- S = g_i^T f_j, exp, write P to LDS ----
#pragma unroll
        for (int fj = 0; fj < 2; fj++) {
            f32x4 sf = {};
#pragma unroll
            for (int ks = 0; ks < 2; ks++) {
                bf16x8 bfr = *(const bf16x8*)(fg + (size_t)(j0 + (fjb+fj)*16 + lr) * 128 + ks*32 + lq*8);
                sf = MFMA16x16x32(a_s[ks], bfr, sf, 0, 0, 0);
            }
#pragma unroll
            for (int t = 0; t < 4; t++) {
                float p = __expf(sf[t]);
                P[fi_s*16 + lq*4 + t][(fjb+fj)*16 + lr] = (bf16)p;
            }
        }
        __syncthreads();

        // ---- read P A-fragments ----
        bf16x8 ap[4][2];
#pragma unroll
        for (int fi = 0; fi < 4; fi++)
#pragma unroll
            for (int ks = 0; ks < 2; ks++)
                ap[fi][ks] = *(const bf16x8*)(&P[fi*16 + lr][ks*32 + lq*8]);

        // ---- wave 0: accumulate row sums l ----
        if (w == 0) {
#pragma unroll
            for (int fi = 0; fi < 4; fi++)
#pragma unroll
                for (int ks = 0; ks < 2; ks++)
#pragma unroll
                    for (int t = 0; t < 8; t++)
                        lacc[fi] += (float)ap[fi][ks][t];
        }

        // ---- PV: O[i][c] += P[i][j] h[c][j] ----
#pragma unroll
        for (int fc = 0; fc < 4; fc++) {
#pragma unroll
            for (int ks = 0; ks < 2; ks++) {
                bf16x8 bh = *(const bf16x8*)(hb + (size_t)(cw + fc*16 + lr) * NN + j0 + ks*32 + lq*8);
#pragma unroll
                for (int fi = 0; fi < 4; fi++)
                    oacc[fi][fc] = MFMA16x16x32(ap[fi][ks], bh, oacc[fi][fc], 0, 0, 0);
            }
        }
        __syncthreads();
    }

    // ---- reduce l, write 1/l ----
    if (w == 0) {
#pragma unroll
        for (int fi = 0; fi < 4; fi++) {
            float v = lacc[fi];
            v += __shfl_xor(v, 16, 64);
            v += __shfl_xor(v, 32, 64);
            if (l < 16) linv[fi*16 + l] = 1.0f / v;
        }
    }
    __syncthreads();

    // ---- epilogue: out = gamma * O/l + x ----
    const float* xb = x + (size_t)b * NC * NN;
    float* ob = out + (size_t)b * NC * NN;
#pragma unroll
    for (int fi = 0; fi < 4; fi++) {
        f32x4 li = *(const f32x4*)&linv[fi*16 + lq*4];
#pragma unroll
        for (int fc = 0; fc < 4; fc++) {
            int c = cw + fc*16 + lr;
            size_t base = (size_t)c * NN + i0 + fi*16 + lq*4;
            float4 xv = *(const float4*)(xb + base);
            float4 ov;
            ov.x = gamma * oacc[fi][fc][0] * li[0] + xv.x;
            ov.y = gamma * oacc[fi][fc][1] * li[1] + xv.y;
            ov.z = gamma * oacc[fi][fc][2] * li[2] + xv.z;
            ov.w = gamma * oacc[fi][fc][3] * li[3] + xv.w;
            *(float4*)(ob + base) = ov;
        }
    }
}

// -------------------- launcher ----------------------------------------------
extern "C" void kernel_launch(void* const* d_in, const int* in_sizes, int n_in,
                              void* d_out, int out_size, void* d_ws, size_t ws_size,
                              hipStream_t stream)
{
    const float* x     = (const float*)d_in[0];
    const float* Wf    = (const float*)d_in[1];
    const float* bf_   = (const float*)d_in[2];
    const float* Wg    = (const float*)d_in[3];
    const float* bg_   = (const float*)d_in[4];
    const float* Wh    = (const float*)d_in[5];
    const float* bh_   = (const float*)d_in[6];
    const float* gamma = (const float*)d_in[7];
    float* out = (float*)d_out;

    char* ws = (char*)d_ws;
    // workspace layout (bytes):
    //   xT  : 8*4096*512*2  = 33,554,432
    //   h   : 8*512*4096*2  = 33,554,432
    //   fgT : 8*4096*128*2  =  8,388,608
    //   Wfg : 128*512*2     =    131,072
    //   Whb : 512*512*2     =    524,288
    //   bfg : 128*4         =        512
    // total ~76.2 MB
    bf16*  xT  = (bf16*)(ws);
    bf16*  hB  = (bf16*)(ws + 33554432);
    bf16*  fgT = (bf16*)(ws + 67108864);
    bf16*  Wfg = (bf16*)(ws + 75497472);
    bf16*  Whb = (bf16*)(ws + 75628544);
    float* bfg = (float*)(ws + 76152832);

    k_wprep<<<dim3(1024), dim3(256), 0, stream>>>(Wf, bf_, Wg, bg_, Wh, Wfg, Whb, bfg);
    k_transpose<<<dim3(64, 8, 8), dim3(256), 0, stream>>>(x, xT);
    // fgT[b][n][o], o in [0,128): A = xT rows (n), B = Wfg rows (o), bias over col
    k_gemm_nt<<<dim3(32, 8), dim3(256), 0, stream>>>(
        xT, (long long)NN * NC, NC,
        Wfg, 0LL, NC,
        fgT, (long long)NN * 128, 128,
        bfg, 0, 2, NC);
    // h[b][o][n]: A = Whb rows (o), B = xT rows (n), bias over row
    k_gemm_nt<<<dim3(128, 8), dim3(256), 0, stream>>>(
        Whb, 0LL, NC,
        xT, (long long)NN * NC, NC,
        hB, (long long)NC * NN, NN,
        bh_, 1, 64, NC);
    k_attn<<<dim3(64, 8), dim3(512), 0, stream>>>(fgT, hB, x, gamma, out);
}

// Round 2
// 309.303 us; speedup vs baseline: 1.7280x; 1.7280x over previous
//
#include <hip/hip_runtime.h>
#include <hip/hip_bf16.h>

typedef __bf16 bf16;
typedef __attribute__((ext_vector_type(8))) __bf16 bf16x8;
typedef __attribute__((ext_vector_type(4))) float f32x4;

#define MFMA16x16x32 __builtin_amdgcn_mfma_f32_16x16x32_bf16

// Problem constants
#define NB 8
#define NC 512
#define NN 4096     // H*W
#define CFG 64

// -------------------- kernel 0: weight prep (fp32 -> bf16, concat) ----------
__global__ __launch_bounds__(256) void k_wprep(
    const float* __restrict__ Wf, const float* __restrict__ bfv,
    const float* __restrict__ Wg, const float* __restrict__ bgv,
    const float* __restrict__ Wh,
    bf16* __restrict__ Wfg, bf16* __restrict__ Whb, float* __restrict__ bfg)
{
    int idx = blockIdx.x * 256 + threadIdx.x;
    if (idx < 32768)       Wfg[idx] = (bf16)Wf[idx];
    else if (idx < 65536)  Wfg[idx] = (bf16)Wg[idx - 32768];
    if (idx < 262144)      Whb[idx] = (bf16)Wh[idx];
    if (idx < 64)          bfg[idx] = bfv[idx];
    else if (idx < 128)    bfg[idx] = bgv[idx - 64];
}

// -------------------- kernel 1: x [B][C][N] fp32 -> xT [B][N][C] bf16 -------
__global__ __launch_bounds__(256) void k_transpose(
    const float* __restrict__ x, bf16* __restrict__ xT)
{
    __shared__ bf16 tile[64][72];
    int b = blockIdx.z, c0 = blockIdx.y * 64, n0 = blockIdx.x * 64;
    int t = threadIdx.x;
    int cl  = t >> 2;
    int seg = (t & 3) * 16;
    const float* src = x + ((size_t)(b * NC + c0 + cl)) * NN + n0 + seg;
#pragma unroll
    for (int u = 0; u < 4; u++) {
        float4 v = ((const float4*)src)[u];
        tile[cl][seg + u*4 + 0] = (bf16)v.x;
        tile[cl][seg + u*4 + 1] = (bf16)v.y;
        tile[cl][seg + u*4 + 2] = (bf16)v.z;
        tile[cl][seg + u*4 + 3] = (bf16)v.w;
    }
    __syncthreads();
    int nl = t >> 2;
    int cs = (t & 3) * 16;
    bf16 buf[16];
#pragma unroll
    for (int u = 0; u < 16; u++) buf[u] = tile[cs + u][nl];
    bf16* dst = xT + ((size_t)(b * NN + n0 + nl)) * NC + c0 + cs;
    ((bf16x8*)dst)[0] = *(bf16x8*)&buf[0];
    ((bf16x8*)dst)[1] = *(bf16x8*)&buf[8];
}

// -------------------- kernel 2a: fg projection GEMM, tiled-fragment output --
// D[n][o] = sum_c xT[n][c] * Wfg[o][c] + bfg[o];  o in [0,128): f=0..63, g=64..127
// Output layout (f and g separately): F[b][n>>4][ks][lane][e] with
//   lane = ((c>>3)&3)*16 + (n&15), ks = c>>5, e = c&7   (c = channel 0..63)
__global__ __launch_bounds__(256) void k_gemm_fg(
    const bf16* __restrict__ xT, const bf16* __restrict__ Wfg,
    const float* __restrict__ bfg,
    bf16* __restrict__ fF, bf16* __restrict__ gF)
{
    int b = blockIdx.y;
    int w = threadIdx.x >> 6, l = threadIdx.x & 63;
    int tile = blockIdx.x * 4 + w;
    int ti = tile >> 1, tj = tile & 1;       // 64 n-tiles x 2 o-tiles
    int lr = l & 15, lq = l >> 4;

    const bf16* Ab = xT + (size_t)b * NN * NC + (size_t)(ti * 64) * NC;
    const bf16* Bb = Wfg + (size_t)(tj * 64) * NC;

    f32x4 acc[4][4] = {};
    for (int k0 = 0; k0 < NC; k0 += 32) {
        bf16x8 a[4], bb[4];
#pragma unroll
        for (int fi = 0; fi < 4; fi++)
            a[fi] = *(const bf16x8*)(Ab + (size_t)(fi*16 + lr) * NC + k0 + lq*8);
#pragma unroll
        for (int fj = 0; fj < 4; fj++)
            bb[fj] = *(const bf16x8*)(Bb + (size_t)(fj*16 + lr) * NC + k0 + lq*8);
#pragma unroll
        for (int fi = 0; fi < 4; fi++)
#pragma unroll
            for (int fj = 0; fj < 4; fj++)
                acc[fi][fj] = MFMA16x16x32(a[fi], bb[fj], acc[fi][fj], 0, 0, 0);
    }
#pragma unroll
    for (int fi = 0; fi < 4; fi++)
#pragma unroll
        for (int fj = 0; fj < 4; fj++)
#pragma unroll
            for (int t = 0; t < 4; t++) {
                int n = ti*64 + fi*16 + lq*4 + t;      // pixel
                int o = tj*64 + fj*16 + lr;            // out channel 0..127
                float v = acc[fi][fj][t] + bfg[o];
                int c = o & 63;
                bf16* dst = (o < 64) ? fF : gF;
                int jt16 = n >> 4, nr = n & 15;
                int ks = c >> 5, lqd = (c >> 3) & 3, e = c & 7;
                size_t off = (((size_t)(b*256 + jt16)*2 + ks)*64 + (lqd*16 + nr))*8 + e;
                dst[off] = (bf16)v;
            }
}

// -------------------- kernel 2b: h projection GEMM, tiled-fragment output ---
// D[c][j] = sum_k Whb[c][k] * xT[j][k] + bh[c]
// Output: hT[b][j>>6][c>>4][ks][lane][e], lane = ((j>>3)&3)*16 + (c&15),
//   ks = (j>>5)&1, e = j&7
__global__ __launch_bounds__(256) void k_gemm_h(
    const bf16* __restrict__ Whb, const bf16* __restrict__ xT,
    const float* __restrict__ bh,
    bf16* __restrict__ hT)
{
    int b = blockIdx.y;
    int w = threadIdx.x >> 6, l = threadIdx.x & 63;
    int tile = blockIdx.x * 4 + w;
    int ti = tile >> 6, tj = tile & 63;      // 8 c-tiles x 64 j-tiles
    int lr = l & 15, lq = l >> 4;

    const bf16* Ab = Whb + (size_t)(ti * 64) * NC;
    const bf16* Bb = xT + (size_t)b * NN * NC + (size_t)(tj * 64) * NC;

    f32x4 acc[4][4] = {};
    for (int k0 = 0; k0 < NC; k0 += 32) {
        bf16x8 a[4], bb[4];
#pragma unroll
        for (int fi = 0; fi < 4; fi++)
            a[fi] = *(const bf16x8*)(Ab + (size_t)(fi*16 + lr) * NC + k0 + lq*8);
#pragma unroll
        for (int fj = 0; fj < 4; fj++)
            bb[fj] = *(const bf16x8*)(Bb + (size_t)(fj*16 + lr) * NC + k0 + lq*8);
#pragma unroll
        for (int fi = 0; fi < 4; fi++)
#pragma unroll
            for (int fj = 0; fj < 4; fj++)
                acc[fi][fj] = MFMA16x16x32(a[fi], bb[fj], acc[fi][fj], 0, 0, 0);
    }
#pragma unroll
    for (int fi = 0; fi < 4; fi++)
#pragma unroll
        for (int fj = 0; fj < 4; fj++)
#pragma unroll
            for (int t = 0; t < 4; t++) {
                int c = ti*64 + fi*16 + lq*4 + t;
                int j = tj*64 + fj*16 + lr;
                float v = acc[fi][fj][t] + bh[c];
                int jt = j >> 6, ks = (j >> 5) & 1, lqd = (j >> 3) & 3, e = j & 7;
                int ct = c >> 4, crd = c & 15;
                size_t off = ((((size_t)(b*64 + jt)*32 + ct)*2 + ks)*64 + (lqd*16 + crd))*8 + e;
                hT[off] = (bf16)v;
            }
}

// -------------------- kernel 3: fused attention -----------------------------
// All fragment loads are fully coalesced (lane-order tiled layouts).
__global__ __launch_bounds__(512, 4) void k_attn(
    const bf16* __restrict__ fF, const bf16* __restrict__ gF,
    const bf16* __restrict__ hT, const float* __restrict__ x,
    const float* __restrict__ gammap, float* __restrict__ out)
{
    __shared__ alignas(16) bf16 P[64][72];
    __shared__ alignas(16) float linv[64];

    int b = blockIdx.y;
    int i0 = blockIdx.x * 64;
    int w = threadIdx.x >> 6, l = threadIdx.x & 63;
    int lr = l & 15, lq = l >> 4;

    float gamma = *gammap;
    int fi_s = w >> 1;
    int fjb  = (w & 1) * 2;

    // hoisted g A-fragments (queries i0 + fi_s*16 ..)
    const bf16* gbase = gF + ((size_t)(b*256 + (i0 >> 4) + fi_s)*2)*512 + (size_t)l*8;
    bf16x8 a_s[2];
    a_s[0] = *(const bf16x8*)(gbase);
    a_s[1] = *(const bf16x8*)(gbase + 512);

    f32x4 oacc[4][4] = {};
    float lacc[4] = {0.f, 0.f, 0.f, 0.f};

    const bf16* fb0 = fF + ((size_t)(b*256 + fjb)*2)*512 + (size_t)l*8;
    const bf16* hb0 = hT + (((size_t)(b*64)*32 + w*4)*2)*512 + (size_t)l*8;

    for (int jt = 0; jt < 64; jt++) {
        // ---- f fragment loads for S (consumed first) ----
        const bf16* fb = fb0 + (size_t)jt * 4096;   // 4 jt16-tiles of 1024 elems
        bf16x8 bf00 = *(const bf16x8*)(fb);
        bf16x8 bf01 = *(const bf16x8*)(fb + 512);
        bf16x8 bf10 = *(const bf16x8*)(fb + 1024);
        bf16x8 bf11 = *(const bf16x8*)(fb + 1536);
        // ---- h fragment prefetch (independent; hides under S+exp+barrier) ----
        const bf16* hb = hb0 + (size_t)jt * 32768;  // 32 ct-tiles of 1024 elems
        bf16x8 bh[4][2];
#pragma unroll
        for (int fc = 0; fc < 4; fc++) {
            bh[fc][0] = *(const bf16x8*)(hb + (fc*2 + 0)*512);
            bh[fc][1] = *(const bf16x8*)(hb + (fc*2 + 1)*512);
        }

        // ---- S = g_i^T f_j (each wave: 1 row-frag x 2 col-frags), exp -> P --
        f32x4 s0 = {}, s1 = {};
        s0 = MFMA16x16x32(a_s[0], bf00, s0, 0, 0, 0);
        s0 = MFMA16x16x32(a_s[1], bf01, s0, 0, 0, 0);
        s1 = MFMA16x16x32(a_s[0], bf10, s1, 0, 0, 0);
        s1 = MFMA16x16x32(a_s[1], bf11, s1, 0, 0, 0);
#pragma unroll
        for (int t = 0; t < 4; t++) {
            P[fi_s*16 + lq*4 + t][fjb*16 + lr]     = (bf16)__expf(s0[t]);
            P[fi_s*16 + lq*4 + t][(fjb+1)*16 + lr] = (bf16)__expf(s1[t]);
        }
        __syncthreads();

        // ---- PV: O[i][c] += P[i][j] h[c][j]; one P-frag pair live at a time --
        __builtin_amdgcn_s_setprio(1);
#pragma unroll
        for (int fi = 0; fi < 4; fi++) {
            bf16x8 ap0 = *(const bf16x8*)(&P[fi*16 + lr][lq*8]);
            bf16x8 ap1 = *(const bf16x8*)(&P[fi*16 + lr][32 + lq*8]);
            if (w == 0) {
                float s = 0.f;
#pragma unroll
                for (int t = 0; t < 8; t++) s += (float)ap0[t] + (float)ap1[t];
                lacc[fi] += s;
            }
#pragma unroll
            for (int fc = 0; fc < 4; fc++) {
                oacc[fi][fc] = MFMA16x16x32(ap0, bh[fc][0], oacc[fi][fc], 0, 0, 0);
                oacc[fi][fc] = MFMA16x16x32(ap1, bh[fc][1], oacc[fi][fc], 0, 0, 0);
            }
        }
        __builtin_amdgcn_s_setprio(0);
        __syncthreads();
    }

    // ---- reduce l, write 1/l ----
    if (w == 0) {
#pragma unroll
        for (int fi = 0; fi < 4; fi++) {
            float v = lacc[fi];
            v += __shfl_xor(v, 16, 64);
            v += __shfl_xor(v, 32, 64);
            if (l < 16) linv[fi*16 + l] = 1.0f / v;
        }
    }
    __syncthreads();

    // ---- epilogue: out = gamma * O/l + x ----
    int cw = w * 64;
    const float* xb = x + (size_t)b * NC * NN;
    float* ob = out + (size_t)b * NC * NN;
#pragma unroll
    for (int fi = 0; fi < 4; fi++) {
        f32x4 li = *(const f32x4*)&linv[fi*16 + lq*4];
#pragma unroll
        for (int fc = 0; fc < 4; fc++) {
            int c = cw + fc*16 + lr;
            size_t base = (size_t)c * NN + i0 + fi*16 + lq*4;
            float4 xv = *(const float4*)(xb + base);
            float4 ov;
            ov.x = gamma * oacc[fi][fc][0] * li[0] + xv.x;
            ov.y = gamma * oacc[fi][fc][1] * li[1] + xv.y;
            ov.z = gamma * oacc[fi][fc][2] * li[2] + xv.z;
            ov.w = gamma * oacc[fi][fc][3] * li[3] + xv.w;
            *(float4*)(ob + base) = ov;
        }
    }
}

// -------------------- launcher ----------------------------------------------
extern "C" void kernel_launch(void* const* d_in, const int* in_sizes, int n_in,
                              void* d_out, int out_size, void* d_ws, size_t ws_size,
                              hipStream_t stream)
{
    const float* x     = (const float*)d_in[0];
    const float* Wf    = (const float*)d_in[1];
    const float* bf_   = (const float*)d_in[2];
    const float* Wg    = (const float*)d_in[3];
    const float* bg_   = (const float*)d_in[4];
    const float* Wh    = (const float*)d_in[5];
    const float* bh_   = (const float*)d_in[6];
    const float* gamma = (const float*)d_in[7];
    float* out = (float*)d_out;

    char* ws = (char*)d_ws;
    // workspace layout (bytes):
    //   xT  : 8*4096*512*2      = 33,554,432
    //   hT  : tiled, same size  = 33,554,432
    //   fF  : 8*4096*64*2       =  4,194,304
    //   gF  : 8*4096*64*2       =  4,194,304
    //   Wfg : 128*512*2         =    131,072
    //   Whb : 512*512*2         =    524,288
    //   bfg : 128*4             =        512
    bf16*  xT  = (bf16*)(ws);
    bf16*  hT  = (bf16*)(ws + 33554432);
    bf16*  fF  = (bf16*)(ws + 67108864);
    bf16*  gF  = (bf16*)(ws + 71303168);
    bf16*  Wfg = (bf16*)(ws + 75497472);
    bf16*  Whb = (bf16*)(ws + 75628544);
    float* bfg = (float*)(ws + 76152832);

    k_wprep<<<dim3(1024), dim3(256), 0, stream>>>(Wf, bf_, Wg, bg_, Wh, Wfg, Whb, bfg);
    k_transpose<<<dim3(64, 8, 8), dim3(256), 0, stream>>>(x, xT);
    k_gemm_fg<<<dim3(32, 8), dim3(256), 0, stream>>>(xT, Wfg, bfg, fF, gF);
    k_gemm_h<<<dim3(128, 8), dim3(256), 0, stream>>>(Whb, xT, bh_, hT);
    k_attn<<<dim3(64, 8), dim3(512), 0, stream>>>(fF, gF, hT, x, gamma, out);
}

// Round 3
// 280.097 us; speedup vs baseline: 1.9082x; 1.1043x over previous
//
#include <hip/hip_runtime.h>
#include <hip/hip_bf16.h>

typedef __bf16 bf16;
typedef __attribute__((ext_vector_type(4))) __bf16 bf16x4;
typedef __attribute__((ext_vector_type(8))) __bf16 bf16x8;
typedef __attribute__((ext_vector_type(4))) float f32x4;

#define MFMA16x16x32 __builtin_amdgcn_mfma_f32_16x16x32_bf16

// Problem constants
#define NB 8
#define NC 512
#define NN 4096     // H*W
#define CFG 64

// -------------------- kernel 0: weight prep (fp32 -> bf16, concat) ----------
__global__ __launch_bounds__(256) void k_wprep(
    const float* __restrict__ Wf, const float* __restrict__ bfv,
    const float* __restrict__ Wg, const float* __restrict__ bgv,
    const float* __restrict__ Wh,
    bf16* __restrict__ Wfg, bf16* __restrict__ Whb, float* __restrict__ bfg)
{
    int idx = blockIdx.x * 256 + threadIdx.x;
    if (idx < 32768)       Wfg[idx] = (bf16)Wf[idx];
    else if (idx < 65536)  Wfg[idx] = (bf16)Wg[idx - 32768];
    if (idx < 262144)      Whb[idx] = (bf16)Wh[idx];
    if (idx < 64)          bfg[idx] = bfv[idx];
    else if (idx < 128)    bfg[idx] = bgv[idx - 64];
}

// -------------------- kernel 1: x [B][C][N] fp32 -> xT [B][N][C] bf16 -------
__global__ __launch_bounds__(256) void k_transpose(
    const float* __restrict__ x, bf16* __restrict__ xT)
{
    __shared__ bf16 tile[64][72];
    int b = blockIdx.z, c0 = blockIdx.y * 64, n0 = blockIdx.x * 64;
    int t = threadIdx.x;
    int cl  = t >> 2;
    int seg = (t & 3) * 16;
    const float* src = x + ((size_t)(b * NC + c0 + cl)) * NN + n0 + seg;
#pragma unroll
    for (int u = 0; u < 4; u++) {
        float4 v = ((const float4*)src)[u];
        tile[cl][seg + u*4 + 0] = (bf16)v.x;
        tile[cl][seg + u*4 + 1] = (bf16)v.y;
        tile[cl][seg + u*4 + 2] = (bf16)v.z;
        tile[cl][seg + u*4 + 3] = (bf16)v.w;
    }
    __syncthreads();
    int nl = t >> 2;
    int cs = (t & 3) * 16;
    bf16 buf[16];
#pragma unroll
    for (int u = 0; u < 16; u++) buf[u] = tile[cs + u][nl];
    bf16* dst = xT + ((size_t)(b * NN + n0 + nl)) * NC + c0 + cs;
    ((bf16x8*)dst)[0] = *(bf16x8*)&buf[0];
    ((bf16x8*)dst)[1] = *(bf16x8*)&buf[8];
}

// -------------------- kernel 2a: fg projection GEMM, tiled-fragment output --
// D[n][o] = sum_c xT[n][c] * Wfg[o][c] + bfg[o];  o in [0,128): f=0..63, g=64..127
// Output layout (f and g separately): F[b][n>>4][ks][lane][e] with
//   lane = ((c>>3)&3)*16 + (n&15), ks = c>>5, e = c&7   (c = channel 0..63)
__global__ __launch_bounds__(256) void k_gemm_fg(
    const bf16* __restrict__ xT, const bf16* __restrict__ Wfg,
    const float* __restrict__ bfg,
    bf16* __restrict__ fF, bf16* __restrict__ gF)
{
    int b = blockIdx.y;
    int w = threadIdx.x >> 6, l = threadIdx.x & 63;
    int tile = blockIdx.x * 4 + w;
    int ti = tile >> 1, tj = tile & 1;       // 64 n-tiles x 2 o-tiles
    int lr = l & 15, lq = l >> 4;

    const bf16* Ab = xT + (size_t)b * NN * NC + (size_t)(ti * 64) * NC;
    const bf16* Bb = Wfg + (size_t)(tj * 64) * NC;

    f32x4 acc[4][4] = {};
    for (int k0 = 0; k0 < NC; k0 += 32) {
        bf16x8 a[4], bb[4];
#pragma unroll
        for (int fi = 0; fi < 4; fi++)
            a[fi] = *(const bf16x8*)(Ab + (size_t)(fi*16 + lr) * NC + k0 + lq*8);
#pragma unroll
        for (int fj = 0; fj < 4; fj++)
            bb[fj] = *(const bf16x8*)(Bb + (size_t)(fj*16 + lr) * NC + k0 + lq*8);
#pragma unroll
        for (int fi = 0; fi < 4; fi++)
#pragma unroll
            for (int fj = 0; fj < 4; fj++)
                acc[fi][fj] = MFMA16x16x32(a[fi], bb[fj], acc[fi][fj], 0, 0, 0);
    }
#pragma unroll
    for (int fi = 0; fi < 4; fi++)
#pragma unroll
        for (int fj = 0; fj < 4; fj++)
#pragma unroll
            for (int t = 0; t < 4; t++) {
                int n = ti*64 + fi*16 + lq*4 + t;      // pixel
                int o = tj*64 + fj*16 + lr;            // out channel 0..127
                float v = acc[fi][fj][t] + bfg[o];
                int c = o & 63;
                bf16* dst = (o < 64) ? fF : gF;
                int jt16 = n >> 4, nr = n & 15;
                int ks = c >> 5, lqd = (c >> 3) & 3, e = c & 7;
                size_t off = (((size_t)(b*256 + jt16)*2 + ks)*64 + (lqd*16 + nr))*8 + e;
                dst[off] = (bf16)v;
            }
}

// -------------------- kernel 2b: h projection GEMM, tiled-fragment output ---
// D[c][j] = sum_k Whb[c][k] * xT[j][k] + bh[c]
// Output: hT[b][j>>6][c>>4][ks][lane][e], lane = ((j>>3)&3)*16 + (c&15),
//   ks = (j>>5)&1, e = j&7
__global__ __launch_bounds__(256) void k_gemm_h(
    const bf16* __restrict__ Whb, const bf16* __restrict__ xT,
    const float* __restrict__ bh,
    bf16* __restrict__ hT)
{
    int b = blockIdx.y;
    int w = threadIdx.x >> 6, l = threadIdx.x & 63;
    int tile = blockIdx.x * 4 + w;
    int ti = tile >> 6, tj = tile & 63;      // 8 c-tiles x 64 j-tiles
    int lr = l & 15, lq = l >> 4;

    const bf16* Ab = Whb + (size_t)(ti * 64) * NC;
    const bf16* Bb = xT + (size_t)b * NN * NC + (size_t)(tj * 64) * NC;

    f32x4 acc[4][4] = {};
    for (int k0 = 0; k0 < NC; k0 += 32) {
        bf16x8 a[4], bb[4];
#pragma unroll
        for (int fi = 0; fi < 4; fi++)
            a[fi] = *(const bf16x8*)(Ab + (size_t)(fi*16 + lr) * NC + k0 + lq*8);
#pragma unroll
        for (int fj = 0; fj < 4; fj++)
            bb[fj] = *(const bf16x8*)(Bb + (size_t)(fj*16 + lr) * NC + k0 + lq*8);
#pragma unroll
        for (int fi = 0; fi < 4; fi++)
#pragma unroll
            for (int fj = 0; fj < 4; fj++)
                acc[fi][fj] = MFMA16x16x32(a[fi], bb[fj], acc[fi][fj], 0, 0, 0);
    }
#pragma unroll
    for (int fi = 0; fi < 4; fi++)
#pragma unroll
        for (int fj = 0; fj < 4; fj++)
#pragma unroll
            for (int t = 0; t < 4; t++) {
                int c = ti*64 + fi*16 + lq*4 + t;
                int j = tj*64 + fj*16 + lr;
                float v = acc[fi][fj][t] + bh[c];
                int jt = j >> 6, ks = (j >> 5) & 1, lqd = (j >> 3) & 3, e = j & 7;
                int ct = c >> 4, crd = c & 15;
                size_t off = ((((size_t)(b*64 + jt)*32 + ct)*2 + ks)*64 + (lqd*16 + crd))*8 + e;
                hT[off] = (bf16)v;
            }
}

// -------------------- kernel 3: fused attention -----------------------------
// Swapped S (mfma(f,g) -> P^T fragments land lane-local for direct b64 LDS
// write in PV-A-fragment layout). P double-buffered, ONE barrier per j-tile.
__global__ __launch_bounds__(512, 4) void k_attn(
    const bf16* __restrict__ fF, const bf16* __restrict__ gF,
    const bf16* __restrict__ hT, const float* __restrict__ x,
    const float* __restrict__ gammap, float* __restrict__ out)
{
    // P LDS in A-fragment layout: [buf][fi][ks][lane][e] (bf16), 16 KB total
    __shared__ alignas(16) bf16 Pl[2][4][2][64][8];
    __shared__ alignas(16) float linv[64];

    int b = blockIdx.y;
    int i0 = blockIdx.x * 64;
    int w = threadIdx.x >> 6, l = threadIdx.x & 63;
    int lr = l & 15, lq = l >> 4;

    float gamma = *gammap;
    int fi_s = w >> 1;     // i-subtile this wave computes in S
    int ks_s = w & 1;      // j32-block (PV k-block) this wave computes

    bf16* Pf = &Pl[0][0][0][0][0];
    // S-output write offset (elems) for fj=0; fj=1 adds 256.
    int wrA = ((fi_s*2 + ks_s)*64 + (lq >> 1)*16 + lr)*8 + (lq & 1)*4;

    // g B-fragments, hoisted (2 channel-halves)
    const bf16* gbase = gF + ((size_t)(b*256 + (i0 >> 4) + fi_s)*2)*512 + (size_t)l*8;
    bf16x8 bg0 = *(const bf16x8*)(gbase);
    bf16x8 bg1 = *(const bf16x8*)(gbase + 512);

    const bf16* fb0 = fF + (size_t)b*256*2*512 + (size_t)l*8;
    const bf16* hb0 = hT + (size_t)b*64*32*2*512 + (size_t)(w*4)*2*512 + (size_t)l*8;

    f32x4 oacc[4][4] = {};
    float lacc[4] = {0.f, 0.f, 0.f, 0.f};

    // ---- S for j-tile jn -> Pl[buf] ----
#define S_STEP(jn, buf)                                                        \
    {                                                                          \
        const bf16* fb = fb0 + (size_t)((jn)*4 + ks_s*2)*1024;                 \
        bf16x8 af00 = *(const bf16x8*)(fb);                                    \
        bf16x8 af01 = *(const bf16x8*)(fb + 512);                              \
        bf16x8 af10 = *(const bf16x8*)(fb + 1024);                             \
        bf16x8 af11 = *(const bf16x8*)(fb + 1536);                             \
        f32x4 s0 = {}, s1 = {};                                                \
        s0 = MFMA16x16x32(af00, bg0, s0, 0, 0, 0);                             \
        s0 = MFMA16x16x32(af01, bg1, s0, 0, 0, 0);                             \
        s1 = MFMA16x16x32(af10, bg0, s1, 0, 0, 0);                             \
        s1 = MFMA16x16x32(af11, bg1, s1, 0, 0, 0);                             \
        bf16x4 p0, p1;                                                         \
        _Pragma("unroll")                                                      \
        for (int t = 0; t < 4; t++) {                                          \
            p0[t] = (bf16)__expf(s0[t]);                                       \
            p1[t] = (bf16)__expf(s1[t]);                                       \
        }                                                                      \
        *(bf16x4*)(Pf + (buf)*4096 + wrA)       = p0;                          \
        *(bf16x4*)(Pf + (buf)*4096 + wrA + 256) = p1;                          \
    }

    // prologue: S(0) -> buf 0
    S_STEP(0, 0)
    __syncthreads();

    for (int jt = 0; jt < 64; jt++) {
        int cur = jt & 1, nxt = cur ^ 1;
        int jn = (jt + 1) & 63;

        // h fragments for PV(jt)
        const bf16* hb = hb0 + (size_t)jt * 32768;
        bf16x8 bh[4][2];
#pragma unroll
        for (int fc = 0; fc < 4; fc++) {
            bh[fc][0] = *(const bf16x8*)(hb + (fc*2 + 0)*512);
            bh[fc][1] = *(const bf16x8*)(hb + (fc*2 + 1)*512);
        }

        // ---- PV(jt) from Pl[cur] ----
        const bf16* Pr = Pf + cur*4096 + l*8;
        __builtin_amdgcn_s_setprio(1);
#pragma unroll
        for (int fi = 0; fi < 4; fi++) {
            bf16x8 ap0 = *(const bf16x8*)(Pr + (fi*2 + 0)*512);
            bf16x8 ap1 = *(const bf16x8*)(Pr + (fi*2 + 1)*512);
            if (w == 0) {
                float s = 0.f;
#pragma unroll
                for (int t = 0; t < 8; t++) s += (float)ap0[t] + (float)ap1[t];
                lacc[fi] += s;
            }
#pragma unroll
            for (int fc = 0; fc < 4; fc++) {
                oacc[fi][fc] = MFMA16x16x32(ap0, bh[fc][0], oacc[fi][fc], 0, 0, 0);
                oacc[fi][fc] = MFMA16x16x32(ap1, bh[fc][1], oacc[fi][fc], 0, 0, 0);
            }
        }
        __builtin_amdgcn_s_setprio(0);

        // ---- S(jt+1) -> Pl[nxt] (redundant at jt=63, harmless) ----
        S_STEP(jn, nxt)

        __syncthreads();
    }
#undef S_STEP

    // ---- reduce l, write 1/l ----
    if (w == 0) {
#pragma unroll
        for (int fi = 0; fi < 4; fi++) {
            float v = lacc[fi];
            v += __shfl_xor(v, 16, 64);
            v += __shfl_xor(v, 32, 64);
            if (l < 16) linv[fi*16 + l] = 1.0f / v;
        }
    }
    __syncthreads();

    // ---- epilogue: out = gamma * O/l + x ----
    int cw = w * 64;
    const float* xb = x + (size_t)b * NC * NN;
    float* ob = out + (size_t)b * NC * NN;
#pragma unroll
    for (int fi = 0; fi < 4; fi++) {
        f32x4 li = *(const f32x4*)&linv[fi*16 + lq*4];
#pragma unroll
        for (int fc = 0; fc < 4; fc++) {
            int c = cw + fc*16 + lr;
            size_t base = (size_t)c * NN + i0 + fi*16 + lq*4;
            float4 xv = *(const float4*)(xb + base);
            float4 ov;
            ov.x = gamma * oacc[fi][fc][0] * li[0] + xv.x;
            ov.y = gamma * oacc[fi][fc][1] * li[1] + xv.y;
            ov.z = gamma * oacc[fi][fc][2] * li[2] + xv.z;
            ov.w = gamma * oacc[fi][fc][3] * li[3] + xv.w;
            *(float4*)(ob + base) = ov;
        }
    }
}

// -------------------- launcher ----------------------------------------------
extern "C" void kernel_launch(void* const* d_in, const int* in_sizes, int n_in,
                              void* d_out, int out_size, void* d_ws, size_t ws_size,
                              hipStream_t stream)
{
    const float* x     = (const float*)d_in[0];
    const float* Wf    = (const float*)d_in[1];
    const float* bf_   = (const float*)d_in[2];
    const float* Wg    = (const float*)d_in[3];
    const float* bg_   = (const float*)d_in[4];
    const float* Wh    = (const float*)d_in[5];
    const float* bh_   = (const float*)d_in[6];
    const float* gamma = (const float*)d_in[7];
    float* out = (float*)d_out;

    char* ws = (char*)d_ws;
    bf16*  xT  = (bf16*)(ws);
    bf16*  hT  = (bf16*)(ws + 33554432);
    bf16*  fF  = (bf16*)(ws + 67108864);
    bf16*  gF  = (bf16*)(ws + 71303168);
    bf16*  Wfg = (bf16*)(ws + 75497472);
    bf16*  Whb = (bf16*)(ws + 75628544);
    float* bfg = (float*)(ws + 76152832);

    k_wprep<<<dim3(1024), dim3(256), 0, stream>>>(Wf, bf_, Wg, bg_, Wh, Wfg, Whb, bfg);
    k_transpose<<<dim3(64, 8, 8), dim3(256), 0, stream>>>(x, xT);
    k_gemm_fg<<<dim3(32, 8), dim3(256), 0, stream>>>(xT, Wfg, bfg, fF, gF);
    k_gemm_h<<<dim3(128, 8), dim3(256), 0, stream>>>(Whb, xT, bh_, hT);
    k_attn<<<dim3(64, 8), dim3(512), 0, stream>>>(fF, gF, hT, x, gamma, out);
}